// Round 4
// baseline (168.892 us; speedup 1.0000x reference)
//
#include <hip/hip_runtime.h>
#include <hip/hip_bf16.h>

// Problem constants (reference: B=2, L=2048, D=1024, H=16, HD=64, LD=256)
#define BB   2
#define LL   2048
#define DD   1024
#define HH   16
#define HDD  64
#define LDIM 256
#define MTOT (BB * LL)   // 4096 rows for all projection GEMMs

using short8  = __attribute__((ext_vector_type(8))) short;  // 8 bf16 (4 VGPRs)
using floatx4 = __attribute__((ext_vector_type(4))) float;  // MFMA C/D frag

static __device__ __forceinline__ unsigned short f2bf(float x) {
  __hip_bfloat16 h = __float2bfloat16(x);
  return *reinterpret_cast<unsigned short*>(&h);
}
static __device__ __forceinline__ unsigned int pk_bf16(float a, float b) {
  return (unsigned int)f2bf(a) | ((unsigned int)f2bf(b) << 16);
}
// async 16B/lane global->LDS; lds base wave-uniform, HW adds lane*16
static __device__ __forceinline__ void load_lds16(const unsigned short* g,
                                                  unsigned short* l) {
  __builtin_amdgcn_global_load_lds(
      (const __attribute__((address_space(1))) unsigned int*)g,
      (__attribute__((address_space(3))) unsigned int*)l, 16, 0, 0);
}
template <int N>
static __device__ __forceinline__ void waitcnt_vm() {
  if constexpr (N == 0) asm volatile("s_waitcnt vmcnt(0)" ::: "memory");
  else if constexpr (N == 2) asm volatile("s_waitcnt vmcnt(2)" ::: "memory");
  else if constexpr (N == 4) asm volatile("s_waitcnt vmcnt(4)" ::: "memory");
  else if constexpr (N == 6) asm volatile("s_waitcnt vmcnt(6)" ::: "memory");
  else if constexpr (N == 8) asm volatile("s_waitcnt vmcnt(8)" ::: "memory");
}
// End-of-pipelined-iteration barrier. MUST drain this wave's LDS reads
// (lgkmcnt) BEFORE the barrier: after the barrier another wave re-stages
// the buffer via DMA, and a still-queued ds_read would see the new data
// (the R10 post-timing divergence). ISA rule: "s_barrier (s_waitcnt first
// if data dep!)".
static __device__ __forceinline__ void lds_drain_barrier() {
  asm volatile("s_waitcnt lgkmcnt(0)\n\ts_barrier" ::: "memory");
}

// ---------------------------------------------------------------------------
// cast fp32 -> bf16, 4 elems/thread
// ---------------------------------------------------------------------------
__global__ __launch_bounds__(256) void cast_bf16(const float* __restrict__ in,
                                                 unsigned short* __restrict__ out,
                                                 int n4) {
  const int i = (blockIdx.x * 256 + threadIdx.x);
  if (i < n4) {
    float4 v = ((const float4*)in)[i];
    ushort4 o;
    o.x = f2bf(v.x); o.y = f2bf(v.y); o.z = f2bf(v.z); o.w = f2bf(v.w);
    ((ushort4*)out)[i] = o;
  }
}

// ---------------------------------------------------------------------------
// fused transpose+cast for all 5 weights: fp32 [R][C] -> bf16 [C][R].
// grid (32,32,5), block (32,8); out-of-range tiles exit early.
// ---------------------------------------------------------------------------
__global__ __launch_bounds__(256) void transpose_cast5(
    const float* __restrict__ Wq, const float* __restrict__ Wkv,
    const float* __restrict__ Wku, const float* __restrict__ Wvu,
    const float* __restrict__ Wo,
    unsigned short* __restrict__ WqT, unsigned short* __restrict__ WkvT,
    unsigned short* __restrict__ WkuT, unsigned short* __restrict__ WvuT,
    unsigned short* __restrict__ WoT) {
  const float* src; unsigned short* dst; int R, C;
  switch (blockIdx.z) {
    case 0:  src = Wq;  dst = WqT;  R = 1024; C = 1024; break;
    case 1:  src = Wkv; dst = WkvT; R = 1024; C = 256;  break;
    case 2:  src = Wku; dst = WkuT; R = 256;  C = 1024; break;
    case 3:  src = Wvu; dst = WvuT; R = 256;  C = 1024; break;
    default: src = Wo;  dst = WoT;  R = 1024; C = 1024; break;
  }
  if ((int)blockIdx.x * 32 >= C || (int)blockIdx.y * 32 >= R) return;

  __shared__ float tile[32][33];
  const int tx = threadIdx.x, ty = threadIdx.y;
#pragma unroll
  for (int i = 0; i < 4; ++i) {
    const int r = blockIdx.y * 32 + ty + i * 8;
    tile[ty + i * 8][tx] = src[(size_t)r * C + blockIdx.x * 32 + tx];
  }
  __syncthreads();
#pragma unroll
  for (int i = 0; i < 4; ++i) {
    const int c = blockIdx.x * 32 + ty + i * 8;
    dst[(size_t)c * R + blockIdx.y * 32 + tx] = f2bf(tile[tx][ty + i * 8]);
  }
}

// ---------------------------------------------------------------------------
// bf16 MFMA GEMM, pipelined K-loop: C = A[M,K] * Bt[N,K]^T.
// Grid (x = M-tiles [fastest], y = N-tiles) for XCD L2 locality on A.
// Tile BMT x BNT, BKT in {32,64}; NW waves (4 -> 2x2, 8 -> 2x4).
// R4: 128x128 tiles for all three big GEMMs (guide tile ladder: 64^2=343,
// 128^2=912 TF measured) -- B-frag reads and staging amortize over 2x the
// MFMAs per K-step vs 128x64. Double-buffered global_load_lds staging;
// prefetch k+1 BEFORE waiting, vmcnt(NLD) + raw s_barrier (never vmcnt(0)
// mid-loop); end-of-iter lds_drain_barrier closes the ds_read vs re-stage
// DMA race.
// KIND 0: fp32 C0[M][N]
// KIND 1: C0 = Qh bf16 [B][H][L][64], C1 = latent bf16 [M][256]
// KIND 2: C0 = Kh bf16 [B][H][L][64], C1 = Vt bf16 [B][H][64][L] (packed st.)
// ---------------------------------------------------------------------------
template <int KIND, int BMT, int BNT, int BKT, int NW = 4>
__global__ __launch_bounds__(NW * 64) void gemm2(const unsigned short* __restrict__ A,
                                                 const unsigned short* __restrict__ Bt0,
                                                 const unsigned short* __restrict__ Bt1,
                                                 void* __restrict__ C0,
                                                 void* __restrict__ C1,
                                                 int M, int N, int K, int nsplit) {
  constexpr int WC = NW / 2;                        // wave grid: 2 x WC
  constexpr int IM = (BMT / 2) / 16;                // row frags per wave
  constexpr int JN = (BNT / WC) / 16;               // col frags per wave
  constexpr int TA = BMT * BKT, TB = BNT * BKT;     // elems per staged tile
  constexpr int EPR = NW * 512;                     // elems per staging inst
  constexpr int NIA = TA / EPR, NIB = TB / EPR;
  constexpr int NLD = NIA + NIB;                    // per-wave loads per k-tile
  constexpr int RPI = EPR / BKT;                    // rows per staging inst
  __shared__ __align__(16) unsigned short As[2 * TA];
  __shared__ __align__(16) unsigned short Bs[2 * TB];

  const int tid  = threadIdx.x;
  const int w    = tid >> 6;
  const int lane = tid & 63;
  const int lo   = lane & 15;
  const int g    = lane >> 4;
  const int wr   = w / WC, wc = w % WC;
  const int row0  = blockIdx.x * BMT;   // M on x (fastest) for XCD locality
  const int col0g = blockIdx.y * BNT;
  const bool second = (col0g >= nsplit);            // block-uniform
  const unsigned short* Btp = second ? Bt1 : Bt0;
  const int col0 = second ? col0g - nsplit : col0g;

  floatx4 acc[IM][JN];
#pragma unroll
  for (int i = 0; i < IM; ++i)
#pragma unroll
    for (int j = 0; j < JN; ++j) acc[i][j] = (floatx4){0.f, 0.f, 0.f, 0.f};

  // staging thread -> (row within inst, k-chunk of 8)
  const int sr = (BKT == 32) ? (tid >> 2) : (tid >> 3);
  const int sc = (BKT == 32) ? (tid & 3) : (tid & 7);

  auto swz = [](int chunk, int row) {
    if constexpr (BKT == 32) return chunk ^ ((row >> 1) & 3);
    else                     return chunk ^ (row & 7);
  };

  auto stage = [&](int buf, int k0) {
#pragma unroll
    for (int inst = 0; inst < NIA; ++inst) {
      const int r  = inst * RPI + sr;
      const int cs = swz(sc, r);
      load_lds16(A + (size_t)(row0 + r) * K + k0 + cs * 8,
                 As + buf * TA + inst * EPR + w * 512);
    }
#pragma unroll
    for (int inst = 0; inst < NIB; ++inst) {
      const int r  = inst * RPI + sr;
      const int cs = swz(sc, r);
      load_lds16(Btp + (size_t)(col0 + r) * K + k0 + cs * 8,
                 Bs + buf * TB + inst * EPR + w * 512);
    }
  };

  const int nk = K / BKT;
  stage(0, 0);                          // prologue
  for (int it = 0; it < nk; ++it) {
    const int cur = it & 1;
    if (it + 1 < nk) {
      stage(cur ^ 1, (it + 1) * BKT);   // prefetch BEFORE waiting
      waitcnt_vm<NLD>();                // only tile-it's loads
    } else {
      waitcnt_vm<0>();
    }
    asm volatile("s_barrier" ::: "memory");

    const unsigned short* Ac = As + cur * TA;
    const unsigned short* Bc = Bs + cur * TB;
#pragma unroll
    for (int kk = 0; kk < BKT / 32; ++kk) {   // sequential kk: caps VGPRs
      short8 af[IM], bf[JN];
#pragma unroll
      for (int i = 0; i < IM; ++i) {
        const int rm = (BMT / 2) * wr + 16 * i + lo;
        af[i] = *(const short8*)(Ac + (size_t)rm * BKT + swz(kk * 4 + g, rm) * 8);
      }
#pragma unroll
      for (int j = 0; j < JN; ++j) {
        const int rn = (BNT / WC) * wc + 16 * j + lo;
        bf[j] = *(const short8*)(Bc + (size_t)rn * BKT + swz(kk * 4 + g, rn) * 8);
      }
#pragma unroll
      for (int i = 0; i < IM; ++i)
#pragma unroll
        for (int j = 0; j < JN; ++j)
          acc[i][j] = __builtin_amdgcn_mfma_f32_16x16x32_bf16(af[i], bf[j], acc[i][j], 0, 0, 0);
    }

    lds_drain_barrier();   // reads done -> cur buf safe for it+2 prefetch
  }

#pragma unroll
  for (int i = 0; i < IM; ++i) {
    const int mbase = row0 + (BMT / 2) * wr + 16 * i + g * 4;
#pragma unroll
    for (int j = 0; j < JN; ++j) {
      const int nl = col0 + (BNT / WC) * wc + 16 * j + lo;
      const int bq = mbase >> 11, hh = nl >> 6, d = nl & 63;
      if (KIND == 2 && second) {
        const int l = mbase & 2047;
        uint2 o;
        o.x = pk_bf16(acc[i][j][0], acc[i][j][1]);
        o.y = pk_bf16(acc[i][j][2], acc[i][j][3]);
        *(uint2*)(&((unsigned short*)C1)[((size_t)(bq * HH + hh) * HDD + d) * LL + l]) = o;
      } else {
#pragma unroll
        for (int r = 0; r < 4; ++r) {
          const float v = acc[i][j][r];
          const int mm = mbase + r;
          const int l = mm & 2047;
          if (KIND == 0) {
            ((float*)C0)[(size_t)mm * N + nl] = v;
          } else if (KIND == 1) {
            if (!second)
              ((unsigned short*)C0)[((size_t)(bq * HH + hh) * LL + l) * HDD + d] = f2bf(v);
            else
              ((unsigned short*)C1)[(size_t)mm * LDIM + nl] = f2bf(v);
          } else {
            ((unsigned short*)C0)[((size_t)(bq * HH + hh) * LL + l) * HDD + d] = f2bf(v);
          }
        }
      }
    }
  }
}

// ---------------------------------------------------------------------------
// MFMA causal flash attention v12: PAIRED-TILE iterations. Each loop
// iteration consumes TWO 64-key tiles with ONE vmcnt wait and ONE drain
// barrier; the two tile bodies are barrier-free back-to-back (P is
// wave-private). 4 staging buffers (K 32K + V 32K + P 16K = 80 KB) keeps
// exactly 2 blocks/CU (160 KB LDS). Pipeline: 2 pairs (4 tiles) in flight;
// steady-state vmcnt(4), last pair vmcnt(2|0), odd tail vmcnt(0).
//   Qh,Kh bf16 [B][H][L][64]; Vt bf16 [B][H][64][L]; y bf16 [B*L][1024].
// ---------------------------------------------------------------------------
#define SC2 0.18033688011112042f   // 0.125 * log2(e)

__global__ __launch_bounds__(512, 4) void flash_mfma12(const unsigned short* __restrict__ Qh,
                                                       const unsigned short* __restrict__ Kh,
                                                       const unsigned short* __restrict__ Vt,
                                                       unsigned short* __restrict__ y) {
  const int w    = threadIdx.x >> 6;
  const int lane = threadIdx.x & 63;
  const int lo   = lane & 15;
  const int g    = lane >> 4;
  const int kw   = w >> 2;         // k-half: 0 -> cols [0,32), 1 -> [32,64)
  const int wq   = w & 3;          // q-row group (16 q) within the 64-q tile
  const int h    = blockIdx.x;
  const int b    = blockIdx.y;
  const int pair = blockIdx.z;     // 0..15
  const int qtH  = 31 - pair;
  const int qtL  = pair;

  __shared__ __align__(16) unsigned short Ks[4 * 64 * 64];     // [buf][k][d] swiz
  __shared__ __align__(16) unsigned short Vs[4 * 64 * 64];     // [buf][d][k] swiz
  __shared__ __align__(16) unsigned short Pq[8][2][16 * 32];   // [wave][H/L][q][k']

  const size_t bh = (size_t)(b * HH + h);
  const unsigned short* Qp = Qh + bh * LL * HDD;
  const unsigned short* Kp = Kh + bh * LL * HDD;
  const unsigned short* Vp = Vt + bh * (size_t)HDD * LL;
  unsigned short* PwH = Pq[w][0];
  unsigned short* PwL = Pq[w][1];

  const int qHw = qtH * 64 + wq * 16;   // this wave's heavy queries
  const int qLw = qtL * 64 + wq * 16;   // this wave's light queries

  // Q B-frags for both q-tiles: B[d=c*32+g*8+j][q=lo]
  short8 qfH0 = *(const short8*)(Qp + (size_t)(qHw + lo) * HDD + g * 8);
  short8 qfH1 = *(const short8*)(Qp + (size_t)(qHw + lo) * HDD + 32 + g * 8);
  short8 qfL0 = *(const short8*)(Qp + (size_t)(qLw + lo) * HDD + g * 8);
  short8 qfL1 = *(const short8*)(Qp + (size_t)(qLw + lo) * HDD + 32 + g * 8);

  floatx4 otH[4], otL[4];
#pragma unroll
  for (int ds = 0; ds < 4; ++ds) {
    otH[ds] = (floatx4){0.f, 0.f, 0.f, 0.f};
    otL[ds] = (floatx4){0.f, 0.f, 0.f, 0.f};
  }
  float lsumH = 0.f, lsumL = 0.f;

  // staging: 8 waves x 1 inst per matrix; wave w covers rows w*8..w*8+7
  const int srow = lane >> 3;   // 8 rows/inst
  const int sch  = lane & 7;

  auto stage = [&](int buf, int k0) {
    const int row = w * 8 + srow;
    const int cs  = sch ^ (row & 7);
    load_lds16(Kp + (size_t)(k0 + row) * HDD + cs * 8, Ks + buf * 4096 + w * 512);
    load_lds16(Vp + (size_t)row * LL + k0 + cs * 8,    Vs + buf * 4096 + w * 512);
  };

  // one 64-key tile: fused-H/L QK^T -> softmax -> PV (no barriers inside;
  // P is wave-private so sm->pv needs no cross-wave sync)
  auto tile_body = [&](int it, int buf) {
    const unsigned short* Kc = Ks + buf * 4096;
    const unsigned short* Vc = Vs + buf * 4096;
    const int k0  = it * 64;
    const bool doL = (it <= qtL);       // block-uniform
    const bool mH  = (it == qtH);
    const bool mL  = (it == qtL);

    floatx4 stH[2], stL[2];
#pragma unroll
    for (int ks = 0; ks < 2; ++ks) {
      const int rm = kw * 32 + ks * 16 + lo;
      short8 a0 = *(const short8*)(Kc + rm * 64 + ((g ^ (rm & 7)) * 8));
      short8 a1 = *(const short8*)(Kc + rm * 64 + (((4 + g) ^ (rm & 7)) * 8));
      floatx4 s = (floatx4){0.f, 0.f, 0.f, 0.f};
      s = __builtin_amdgcn_mfma_f32_16x16x32_bf16(a0, qfH0, s, 0, 0, 0);
      s = __builtin_amdgcn_mfma_f32_16x16x32_bf16(a1, qfH1, s, 0, 0, 0);
      stH[ks] = s;
      if (doL) {
        floatx4 t = (floatx4){0.f, 0.f, 0.f, 0.f};
        t = __builtin_amdgcn_mfma_f32_16x16x32_bf16(a0, qfL0, t, 0, 0, 0);
        t = __builtin_amdgcn_mfma_f32_16x16x32_bf16(a1, qfL1, t, 0, 0, 0);
        stL[ks] = t;
      }
    }

    auto sm = [&](floatx4* st, unsigned short* P, float& lsum, int qw,
                  bool masked) {
      if (!masked) {
#pragma unroll
        for (int ks = 0; ks < 2; ++ks) {
          float p[4];
#pragma unroll
          for (int r = 0; r < 4; ++r) {
            p[r] = __builtin_amdgcn_exp2f(st[ks][r] * SC2);
            lsum += p[r];
          }
          uint2 w2;
          w2.x = pk_bf16(p[0], p[1]);
          w2.y = pk_bf16(p[2], p[3]);
          *(uint2*)(P + lo * 32 + (((ks * 2 + (g >> 1)) ^ (lo & 3)) * 8) + (g & 1) * 4) = w2;
        }
      } else {
        const int qq = qw + lo;
#pragma unroll
        for (int ks = 0; ks < 2; ++ks) {
          float p[4];
#pragma unroll
          for (int r = 0; r < 4; ++r) {
            const int kk = k0 + kw * 32 + ks * 16 + g * 4 + r;
            const float e = __builtin_amdgcn_exp2f(st[ks][r] * SC2);
            p[r] = (kk <= qq) ? e : 0.f;
            lsum += p[r];
          }
          uint2 w2;
          w2.x = pk_bf16(p[0], p[1]);
          w2.y = pk_bf16(p[2], p[3]);
          *(uint2*)(P + lo * 32 + (((ks * 2 + (g >> 1)) ^ (lo & 3)) * 8) + (g & 1) * 4) = w2;
        }
      }
    };
    sm(stH, PwH, lsumH, qHw, mH);
    if (doL) sm(stL, PwL, lsumL, qLw, mL);

    short8 pfH = *(const short8*)(PwH + lo * 32 + ((g ^ (lo & 3)) * 8));
    short8 pfL;
    if (doL) pfL = *(const short8*)(PwL + lo * 32 + ((g ^ (lo & 3)) * 8));
#pragma unroll
    for (int ds = 0; ds < 4; ++ds) {
      const int rm = ds * 16 + lo;
      short8 v = *(const short8*)(Vc + rm * 64 + (((kw * 4 + g) ^ (rm & 7)) * 8));
      otH[ds] = __builtin_amdgcn_mfma_f32_16x16x32_bf16(v, pfH, otH[ds], 0, 0, 0);
      if (doL)
        otL[ds] = __builtin_amdgcn_mfma_f32_16x16x32_bf16(v, pfL, otL[ds], 0, 0, 0);
    }
  };

  const int ntiles = qtH + 1;     // >= 17 always
  const int np  = ntiles >> 1;
  const bool odd = (ntiles & 1);

  // prologue: 2 pairs (4 tiles, 8 loads) in flight; ntiles >= 17 > 4 always
  stage(0, 0); stage(1, 64); stage(2, 128); stage(3, 192);

  for (int j = 0; j < np; ++j) {
    const int t0 = 2 * j;
    if (j + 1 < np)      waitcnt_vm<4>();   // pair j done; next pair in flight
    else if (odd)        waitcnt_vm<2>();   // tail tile still in flight
    else                 waitcnt_vm<0>();
    asm volatile("s_barrier" ::: "memory");

    tile_body(t0,     t0 & 3);
    tile_body(t0 + 1, (t0 + 1) & 3);

    lds_drain_barrier();   // reads done -> pair-j bufs safe for re-stage
    const int tp = t0 + 4;
    if (tp < ntiles)     stage(tp & 3, tp * 64);
    if (tp + 1 < ntiles) stage((tp + 1) & 3, (tp + 1) * 64);
  }
  if (odd) {
    const int t = ntiles - 1;
    waitcnt_vm<0>();
    asm volatile("s_barrier" ::: "memory");
    tile_body(t, t & 3);
    lds_drain_barrier();   // all K/V reads done before epilogue reuses LDS
  }

  // ---- cross-k-half combine (reuse dead K/V/P LDS as fp32 scratch) ----
  float sH = lsumH; sH += __shfl_xor(sH, 16); sH += __shfl_xor(sH, 32);
  float sL = lsumL; sL += __shfl_xor(sL, 16); sL += __shfl_xor(sL, 32);
  float* oshH = (float*)Ks;              // [4][64][16] = 16 KiB <= 32 KiB
  float* oshL = (float*)Vs;              // [4][64][16]
  float* lsh  = (float*)&Pq[0][0][0];    // [2][4][16] = 512 B

  if (kw == 1) {
    const int base = (wq * 64 + lane) * 16;
#pragma unroll
    for (int ds = 0; ds < 4; ++ds) {
      *(floatx4*)(oshH + base + ds * 4) = otH[ds];
      *(floatx4*)(oshL + base + ds * 4) = otL[ds];
    }
    if (lane < 16) {
      lsh[wq * 16 + lane]      = sH;
      lsh[64 + wq * 16 + lane] = sL;
    }
  }
  __syncthreads();
  if (kw == 0) {
    const int base = (wq * 64 + lane) * 16;
#pragma unroll
    for (int ds = 0; ds < 4; ++ds) {
      otH[ds] += *(const floatx4*)(oshH + base + ds * 4);
      otL[ds] += *(const floatx4*)(oshL + base + ds * 4);
    }
    sH += lsh[wq * 16 + lo];
    sL += lsh[64 + wq * 16 + lo];

    auto finish = [&](floatx4* ot, float stot, int qw) {
      const float inv = 1.0f / stot;
#pragma unroll
      for (int ds = 0; ds < 4; ++ds) {
        uint2 o;
        o.x = pk_bf16(ot[ds][0] * inv, ot[ds][1] * inv);
        o.y = pk_bf16(ot[ds][2] * inv, ot[ds][3] * inv);
        *(uint2*)(y + (size_t)(b * LL + qw + lo) * (HH * HDD) + h * HDD + ds * 16 + g * 4) = o;
      }
    };
    finish(otH, sH, qHw);
    finish(otL, sL, qLw);
  }
}

// ---------------------------------------------------------------------------
// Launch
// ---------------------------------------------------------------------------
extern "C" void kernel_launch(void* const* d_in, const int* in_sizes, int n_in,
                              void* d_out, int out_size, void* d_ws, size_t ws_size,
                              hipStream_t stream) {
  const float* x   = (const float*)d_in[0];  // [4096][1024]
  const float* Wq  = (const float*)d_in[1];  // [1024][1024]
  const float* Wkv = (const float*)d_in[2];  // [1024][256]
  const float* Wku = (const float*)d_in[3];  // [256][1024]
  const float* Wvu = (const float*)d_in[4];  // [256][1024]
  const float* Wo  = (const float*)d_in[5];  // [1024][1024]
  float* out = (float*)d_out;                // [4096][1024] fp32

  // workspace (bf16 elements)
  unsigned short* xb     = (unsigned short*)d_ws;          // 4096x1024
  unsigned short* WqT    = xb + (size_t)MTOT * DD;         // 1024x1024 [N][K]
  unsigned short* WkvT   = WqT + 1024 * 1024;              // 256x1024
  unsigned short* WkuT   = WkvT + 256 * 1024;              // 1024x256
  unsigned short* WvuT   = WkuT + 1024 * 256;              // 1024x256
  unsigned short* WoT    = WvuT + 1024 * 256;              // 1024x1024
  unsigned short* latent = WoT + 1024 * 1024;              // 4096x256
  unsigned short* Qh     = latent + (size_t)MTOT * LDIM;   // 4096x1024
  unsigned short* Kh     = Qh + (size_t)MTOT * DD;
  unsigned short* Vt     = Kh + (size_t)MTOT * DD;
  unsigned short* y      = Vt + (size_t)MTOT * DD;

  // prep
  cast_bf16<<<dim3(MTOT * DD / 1024), dim3(256), 0, stream>>>(x, xb, MTOT * DD / 4);
  transpose_cast5<<<dim3(32, 32, 5), dim3(32, 8), 0, stream>>>(
      Wq, Wkv, Wku, Wvu, Wo, WqT, WkvT, WkuT, WvuT, WoT);

  // fused Q + latent:  [4096,1024] x [1024, 1024+256]   (128x128, BK=64)
  gemm2<1, 128, 128, 64><<<dim3(MTOT / 128, 1280 / 128), dim3(256), 0, stream>>>(
      xb, WqT, WkvT, Qh, latent, MTOT, 1280, DD, 1024);
  // fused K + V:       [4096,256] x [256, 1024+1024]    (128x128, BK=64)
  gemm2<2, 128, 128, 64><<<dim3(MTOT / 128, 2048 / 128), dim3(256), 0, stream>>>(
      latent, WkuT, WvuT, Kh, Vt, MTOT, 2048, LDIM, 1024);

  // attention (paired-tile k-split flash v12; h fastest for XCD L2)
  flash_mfma12<<<dim3(HH, BB, 16), dim3(512), 0, stream>>>(Qh, Kh, Vt, y);

  // output projection (fp32 out; 128x128, BK=64, 8 waves)
  gemm2<0, 128, 128, 64, 8><<<dim3(MTOT / 128, DD / 128), dim3(512), 0, stream>>>(
      y, WoT, nullptr, out, nullptr, MTOT, DD, DD, DD);
}

// Round 5
// 160.909 us; speedup vs baseline: 1.0496x; 1.0496x over previous
//
#include <hip/hip_runtime.h>
#include <hip/hip_bf16.h>

// Problem constants (reference: B=2, L=2048, D=1024, H=16, HD=64, LD=256)
#define BB   2
#define LL   2048
#define DD   1024
#define HH   16
#define HDD  64
#define LDIM 256
#define MTOT (BB * LL)   // 4096 rows for all projection GEMMs

using short8  = __attribute__((ext_vector_type(8))) short;  // 8 bf16 (4 VGPRs)
using floatx4 = __attribute__((ext_vector_type(4))) float;  // MFMA C/D frag

static __device__ __forceinline__ unsigned short f2bf(float x) {
  __hip_bfloat16 h = __float2bfloat16(x);
  return *reinterpret_cast<unsigned short*>(&h);
}
static __device__ __forceinline__ unsigned int pk_bf16(float a, float b) {
  return (unsigned int)f2bf(a) | ((unsigned int)f2bf(b) << 16);
}
// async 16B/lane global->LDS; lds base wave-uniform, HW adds lane*16
static __device__ __forceinline__ void load_lds16(const unsigned short* g,
                                                  unsigned short* l) {
  __builtin_amdgcn_global_load_lds(
      (const __attribute__((address_space(1))) unsigned int*)g,
      (__attribute__((address_space(3))) unsigned int*)l, 16, 0, 0);
}
template <int N>
static __device__ __forceinline__ void waitcnt_vm() {
  if constexpr (N == 0) asm volatile("s_waitcnt vmcnt(0)" ::: "memory");
  else if constexpr (N == 2) asm volatile("s_waitcnt vmcnt(2)" ::: "memory");
  else if constexpr (N == 4) asm volatile("s_waitcnt vmcnt(4)" ::: "memory");
  else if constexpr (N == 6) asm volatile("s_waitcnt vmcnt(6)" ::: "memory");
  else if constexpr (N == 8) asm volatile("s_waitcnt vmcnt(8)" ::: "memory");
}
// End-of-pipelined-iteration barrier. MUST drain this wave's LDS reads
// (lgkmcnt) BEFORE the barrier: after the barrier another wave re-stages
// the buffer via DMA, and a still-queued ds_read would see the new data
// (the R10 post-timing divergence). ISA rule: "s_barrier (s_waitcnt first
// if data dep!)".
static __device__ __forceinline__ void lds_drain_barrier() {
  asm volatile("s_waitcnt lgkmcnt(0)\n\ts_barrier" ::: "memory");
}

// ---------------------------------------------------------------------------
// cast fp32 -> bf16, 4 elems/thread
// ---------------------------------------------------------------------------
__global__ __launch_bounds__(256) void cast_bf16(const float* __restrict__ in,
                                                 unsigned short* __restrict__ out,
                                                 int n4) {
  const int i = (blockIdx.x * 256 + threadIdx.x);
  if (i < n4) {
    float4 v = ((const float4*)in)[i];
    ushort4 o;
    o.x = f2bf(v.x); o.y = f2bf(v.y); o.z = f2bf(v.z); o.w = f2bf(v.w);
    ((ushort4*)out)[i] = o;
  }
}

// ---------------------------------------------------------------------------
// fused transpose+cast for all 5 weights: fp32 [R][C] -> bf16 [C][R].
// grid (32,32,5), block (32,8); out-of-range tiles exit early.
// ---------------------------------------------------------------------------
__global__ __launch_bounds__(256) void transpose_cast5(
    const float* __restrict__ Wq, const float* __restrict__ Wkv,
    const float* __restrict__ Wku, const float* __restrict__ Wvu,
    const float* __restrict__ Wo,
    unsigned short* __restrict__ WqT, unsigned short* __restrict__ WkvT,
    unsigned short* __restrict__ WkuT, unsigned short* __restrict__ WvuT,
    unsigned short* __restrict__ WoT) {
  const float* src; unsigned short* dst; int R, C;
  switch (blockIdx.z) {
    case 0:  src = Wq;  dst = WqT;  R = 1024; C = 1024; break;
    case 1:  src = Wkv; dst = WkvT; R = 1024; C = 256;  break;
    case 2:  src = Wku; dst = WkuT; R = 256;  C = 1024; break;
    case 3:  src = Wvu; dst = WvuT; R = 256;  C = 1024; break;
    default: src = Wo;  dst = WoT;  R = 1024; C = 1024; break;
  }
  if ((int)blockIdx.x * 32 >= C || (int)blockIdx.y * 32 >= R) return;

  __shared__ float tile[32][33];
  const int tx = threadIdx.x, ty = threadIdx.y;
#pragma unroll
  for (int i = 0; i < 4; ++i) {
    const int r = blockIdx.y * 32 + ty + i * 8;
    tile[ty + i * 8][tx] = src[(size_t)r * C + blockIdx.x * 32 + tx];
  }
  __syncthreads();
#pragma unroll
  for (int i = 0; i < 4; ++i) {
    const int c = blockIdx.x * 32 + ty + i * 8;
    dst[(size_t)c * R + blockIdx.y * 32 + tx] = f2bf(tile[tx][ty + i * 8]);
  }
}

// ---------------------------------------------------------------------------
// bf16 MFMA GEMM, pipelined K-loop: C = A[M,K] * Bt[N,K]^T.
// Grid (x = M-tiles [fastest], y = N-tiles) for XCD L2 locality on A.
// Tile BMT x BNT, BKT in {32,64}; NW waves (4 -> 2x2, 8 -> 2x4).
// R4 LESSON: at these small N, grid-to-CU quantization dominates tile-size
// amortization. 128x64 tiles -> 640/512-block grids (>=2/CU balanced) beat
// 128x128 -> 320-block grids (1.25/CU, ~40% makespan waste). Launch configs
// below are the R3 set (162.5 us).
// KIND 0: fp32 C0[M][N]
// KIND 1: C0 = Qh bf16 [B][H][L][64], C1 = latent bf16 [M][256]
// KIND 2: C0 = Kh bf16 [B][H][L][64], C1 = Vt bf16 [B][H][64][L] (packed st.)
// ---------------------------------------------------------------------------
template <int KIND, int BMT, int BNT, int BKT, int NW = 4>
__global__ __launch_bounds__(NW * 64) void gemm2(const unsigned short* __restrict__ A,
                                                 const unsigned short* __restrict__ Bt0,
                                                 const unsigned short* __restrict__ Bt1,
                                                 void* __restrict__ C0,
                                                 void* __restrict__ C1,
                                                 int M, int N, int K, int nsplit) {
  constexpr int WC = NW / 2;                        // wave grid: 2 x WC
  constexpr int IM = (BMT / 2) / 16;                // row frags per wave
  constexpr int JN = (BNT / WC) / 16;               // col frags per wave
  constexpr int TA = BMT * BKT, TB = BNT * BKT;     // elems per staged tile
  constexpr int EPR = NW * 512;                     // elems per staging inst
  constexpr int NIA = TA / EPR, NIB = TB / EPR;
  constexpr int NLD = NIA + NIB;                    // per-wave loads per k-tile
  constexpr int RPI = EPR / BKT;                    // rows per staging inst
  __shared__ __align__(16) unsigned short As[2 * TA];
  __shared__ __align__(16) unsigned short Bs[2 * TB];

  const int tid  = threadIdx.x;
  const int w    = tid >> 6;
  const int lane = tid & 63;
  const int lo   = lane & 15;
  const int g    = lane >> 4;
  const int wr   = w / WC, wc = w % WC;
  const int row0  = blockIdx.x * BMT;   // M on x (fastest) for XCD locality
  const int col0g = blockIdx.y * BNT;
  const bool second = (col0g >= nsplit);            // block-uniform
  const unsigned short* Btp = second ? Bt1 : Bt0;
  const int col0 = second ? col0g - nsplit : col0g;

  floatx4 acc[IM][JN];
#pragma unroll
  for (int i = 0; i < IM; ++i)
#pragma unroll
    for (int j = 0; j < JN; ++j) acc[i][j] = (floatx4){0.f, 0.f, 0.f, 0.f};

  // staging thread -> (row within inst, k-chunk of 8)
  const int sr = (BKT == 32) ? (tid >> 2) : (tid >> 3);
  const int sc = (BKT == 32) ? (tid & 3) : (tid & 7);

  auto swz = [](int chunk, int row) {
    if constexpr (BKT == 32) return chunk ^ ((row >> 1) & 3);
    else                     return chunk ^ (row & 7);
  };

  auto stage = [&](int buf, int k0) {
#pragma unroll
    for (int inst = 0; inst < NIA; ++inst) {
      const int r  = inst * RPI + sr;
      const int cs = swz(sc, r);
      load_lds16(A + (size_t)(row0 + r) * K + k0 + cs * 8,
                 As + buf * TA + inst * EPR + w * 512);
    }
#pragma unroll
    for (int inst = 0; inst < NIB; ++inst) {
      const int r  = inst * RPI + sr;
      const int cs = swz(sc, r);
      load_lds16(Btp + (size_t)(col0 + r) * K + k0 + cs * 8,
                 Bs + buf * TB + inst * EPR + w * 512);
    }
  };

  const int nk = K / BKT;
  stage(0, 0);                          // prologue
  for (int it = 0; it < nk; ++it) {
    const int cur = it & 1;
    if (it + 1 < nk) {
      stage(cur ^ 1, (it + 1) * BKT);   // prefetch BEFORE waiting
      waitcnt_vm<NLD>();                // only tile-it's loads
    } else {
      waitcnt_vm<0>();
    }
    asm volatile("s_barrier" ::: "memory");

    const unsigned short* Ac = As + cur * TA;
    const unsigned short* Bc = Bs + cur * TB;
#pragma unroll
    for (int kk = 0; kk < BKT / 32; ++kk) {   // sequential kk: caps VGPRs
      short8 af[IM], bf[JN];
#pragma unroll
      for (int i = 0; i < IM; ++i) {
        const int rm = (BMT / 2) * wr + 16 * i + lo;
        af[i] = *(const short8*)(Ac + (size_t)rm * BKT + swz(kk * 4 + g, rm) * 8);
      }
#pragma unroll
      for (int j = 0; j < JN; ++j) {
        const int rn = (BNT / WC) * wc + 16 * j + lo;
        bf[j] = *(const short8*)(Bc + (size_t)rn * BKT + swz(kk * 4 + g, rn) * 8);
      }
#pragma unroll
      for (int i = 0; i < IM; ++i)
#pragma unroll
        for (int j = 0; j < JN; ++j)
          acc[i][j] = __builtin_amdgcn_mfma_f32_16x16x32_bf16(af[i], bf[j], acc[i][j], 0, 0, 0);
    }

    lds_drain_barrier();   // reads done -> cur buf safe for it+2 prefetch
  }

#pragma unroll
  for (int i = 0; i < IM; ++i) {
    const int mbase = row0 + (BMT / 2) * wr + 16 * i + g * 4;
#pragma unroll
    for (int j = 0; j < JN; ++j) {
      const int nl = col0 + (BNT / WC) * wc + 16 * j + lo;
      const int bq = mbase >> 11, hh = nl >> 6, d = nl & 63;
      if (KIND == 2 && second) {
        const int l = mbase & 2047;
        uint2 o;
        o.x = pk_bf16(acc[i][j][0], acc[i][j][1]);
        o.y = pk_bf16(acc[i][j][2], acc[i][j][3]);
        *(uint2*)(&((unsigned short*)C1)[((size_t)(bq * HH + hh) * HDD + d) * LL + l]) = o;
      } else {
#pragma unroll
        for (int r = 0; r < 4; ++r) {
          const float v = acc[i][j][r];
          const int mm = mbase + r;
          const int l = mm & 2047;
          if (KIND == 0) {
            ((float*)C0)[(size_t)mm * N + nl] = v;
          } else if (KIND == 1) {
            if (!second)
              ((unsigned short*)C0)[((size_t)(bq * HH + hh) * LL + l) * HDD + d] = f2bf(v);
            else
              ((unsigned short*)C1)[(size_t)mm * LDIM + nl] = f2bf(v);
          } else {
            ((unsigned short*)C0)[((size_t)(bq * HH + hh) * LL + l) * HDD + d] = f2bf(v);
          }
        }
      }
    }
  }
}

// ---------------------------------------------------------------------------
// MFMA causal flash attention v13: v12 paired-tile structure + T5 setprio.
// Each loop iteration consumes TWO 64-key tiles with ONE vmcnt wait and ONE
// drain barrier; the two tile bodies are barrier-free back-to-back (P is
// wave-private). s_setprio(1) wraps the QK and PV MFMA clusters: with 8
// role-drifting waves/block x 2 blocks/CU, compute-phase waves win issue
// arbitration over staging-phase waves (guide m191/m218b: +4-7% attn;
// null only in lockstep structures).
//   Qh,Kh bf16 [B][H][L][64]; Vt bf16 [B][H][64][L]; y bf16 [B*L][1024].
// ---------------------------------------------------------------------------
#define SC2 0.18033688011112042f   // 0.125 * log2(e)

__global__ __launch_bounds__(512, 4) void flash_mfma13(const unsigned short* __restrict__ Qh,
                                                       const unsigned short* __restrict__ Kh,
                                                       const unsigned short* __restrict__ Vt,
                                                       unsigned short* __restrict__ y) {
  const int w    = threadIdx.x >> 6;
  const int lane = threadIdx.x & 63;
  const int lo   = lane & 15;
  const int g    = lane >> 4;
  const int kw   = w >> 2;         // k-half: 0 -> cols [0,32), 1 -> [32,64)
  const int wq   = w & 3;          // q-row group (16 q) within the 64-q tile
  const int h    = blockIdx.x;
  const int b    = blockIdx.y;
  const int pair = blockIdx.z;     // 0..15
  const int qtH  = 31 - pair;
  const int qtL  = pair;

  __shared__ __align__(16) unsigned short Ks[4 * 64 * 64];     // [buf][k][d] swiz
  __shared__ __align__(16) unsigned short Vs[4 * 64 * 64];     // [buf][d][k] swiz
  __shared__ __align__(16) unsigned short Pq[8][2][16 * 32];   // [wave][H/L][q][k']

  const size_t bh = (size_t)(b * HH + h);
  const unsigned short* Qp = Qh + bh * LL * HDD;
  const unsigned short* Kp = Kh + bh * LL * HDD;
  const unsigned short* Vp = Vt + bh * (size_t)HDD * LL;
  unsigned short* PwH = Pq[w][0];
  unsigned short* PwL = Pq[w][1];

  const int qHw = qtH * 64 + wq * 16;   // this wave's heavy queries
  const int qLw = qtL * 64 + wq * 16;   // this wave's light queries

  // Q B-frags for both q-tiles: B[d=c*32+g*8+j][q=lo]
  short8 qfH0 = *(const short8*)(Qp + (size_t)(qHw + lo) * HDD + g * 8);
  short8 qfH1 = *(const short8*)(Qp + (size_t)(qHw + lo) * HDD + 32 + g * 8);
  short8 qfL0 = *(const short8*)(Qp + (size_t)(qLw + lo) * HDD + g * 8);
  short8 qfL1 = *(const short8*)(Qp + (size_t)(qLw + lo) * HDD + 32 + g * 8);

  floatx4 otH[4], otL[4];
#pragma unroll
  for (int ds = 0; ds < 4; ++ds) {
    otH[ds] = (floatx4){0.f, 0.f, 0.f, 0.f};
    otL[ds] = (floatx4){0.f, 0.f, 0.f, 0.f};
  }
  float lsumH = 0.f, lsumL = 0.f;

  // staging: 8 waves x 1 inst per matrix; wave w covers rows w*8..w*8+7
  const int srow = lane >> 3;   // 8 rows/inst
  const int sch  = lane & 7;

  auto stage = [&](int buf, int k0) {
    const int row = w * 8 + srow;
    const int cs  = sch ^ (row & 7);
    load_lds16(Kp + (size_t)(k0 + row) * HDD + cs * 8, Ks + buf * 4096 + w * 512);
    load_lds16(Vp + (size_t)row * LL + k0 + cs * 8,    Vs + buf * 4096 + w * 512);
  };

  // one 64-key tile: fused-H/L QK^T -> softmax -> PV (no barriers inside;
  // P is wave-private so sm->pv needs no cross-wave sync)
  auto tile_body = [&](int it, int buf) {
    const unsigned short* Kc = Ks + buf * 4096;
    const unsigned short* Vc = Vs + buf * 4096;
    const int k0  = it * 64;
    const bool doL = (it <= qtL);       // block-uniform
    const bool mH  = (it == qtH);
    const bool mL  = (it == qtL);

    floatx4 stH[2], stL[2];
    __builtin_amdgcn_s_setprio(1);      // T5: favor QK MFMA cluster
#pragma unroll
    for (int ks = 0; ks < 2; ++ks) {
      const int rm = kw * 32 + ks * 16 + lo;
      short8 a0 = *(const short8*)(Kc + rm * 64 + ((g ^ (rm & 7)) * 8));
      short8 a1 = *(const short8*)(Kc + rm * 64 + (((4 + g) ^ (rm & 7)) * 8));
      floatx4 s = (floatx4){0.f, 0.f, 0.f, 0.f};
      s = __builtin_amdgcn_mfma_f32_16x16x32_bf16(a0, qfH0, s, 0, 0, 0);
      s = __builtin_amdgcn_mfma_f32_16x16x32_bf16(a1, qfH1, s, 0, 0, 0);
      stH[ks] = s;
      if (doL) {
        floatx4 t = (floatx4){0.f, 0.f, 0.f, 0.f};
        t = __builtin_amdgcn_mfma_f32_16x16x32_bf16(a0, qfL0, t, 0, 0, 0);
        t = __builtin_amdgcn_mfma_f32_16x16x32_bf16(a1, qfL1, t, 0, 0, 0);
        stL[ks] = t;
      }
    }
    __builtin_amdgcn_s_setprio(0);

    auto sm = [&](floatx4* st, unsigned short* P, float& lsum, int qw,
                  bool masked) {
      if (!masked) {
#pragma unroll
        for (int ks = 0; ks < 2; ++ks) {
          float p[4];
#pragma unroll
          for (int r = 0; r < 4; ++r) {
            p[r] = __builtin_amdgcn_exp2f(st[ks][r] * SC2);
            lsum += p[r];
          }
          uint2 w2;
          w2.x = pk_bf16(p[0], p[1]);
          w2.y = pk_bf16(p[2], p[3]);
          *(uint2*)(P + lo * 32 + (((ks * 2 + (g >> 1)) ^ (lo & 3)) * 8) + (g & 1) * 4) = w2;
        }
      } else {
        const int qq = qw + lo;
#pragma unroll
        for (int ks = 0; ks < 2; ++ks) {
          float p[4];
#pragma unroll
          for (int r = 0; r < 4; ++r) {
            const int kk = k0 + kw * 32 + ks * 16 + g * 4 + r;
            const float e = __builtin_amdgcn_exp2f(st[ks][r] * SC2);
            p[r] = (kk <= qq) ? e : 0.f;
            lsum += p[r];
          }
          uint2 w2;
          w2.x = pk_bf16(p[0], p[1]);
          w2.y = pk_bf16(p[2], p[3]);
          *(uint2*)(P + lo * 32 + (((ks * 2 + (g >> 1)) ^ (lo & 3)) * 8) + (g & 1) * 4) = w2;
        }
      }
    };
    sm(stH, PwH, lsumH, qHw, mH);
    if (doL) sm(stL, PwL, lsumL, qLw, mL);

    short8 pfH = *(const short8*)(PwH + lo * 32 + ((g ^ (lo & 3)) * 8));
    short8 pfL;
    if (doL) pfL = *(const short8*)(PwL + lo * 32 + ((g ^ (lo & 3)) * 8));
    __builtin_amdgcn_s_setprio(1);      // T5: favor PV MFMA cluster
#pragma unroll
    for (int ds = 0; ds < 4; ++ds) {
      const int rm = ds * 16 + lo;
      short8 v = *(const short8*)(Vc + rm * 64 + (((kw * 4 + g) ^ (rm & 7)) * 8));
      otH[ds] = __builtin_amdgcn_mfma_f32_16x16x32_bf16(v, pfH, otH[ds], 0, 0, 0);
      if (doL)
        otL[ds] = __builtin_amdgcn_mfma_f32_16x16x32_bf16(v, pfL, otL[ds], 0, 0, 0);
    }
    __builtin_amdgcn_s_setprio(0);
  };

  const int ntiles = qtH + 1;     // >= 17 always
  const int np  = ntiles >> 1;
  const bool odd = (ntiles & 1);

  // prologue: 2 pairs (4 tiles, 8 loads) in flight; ntiles >= 17 > 4 always
  stage(0, 0); stage(1, 64); stage(2, 128); stage(3, 192);

  for (int j = 0; j < np; ++j) {
    const int t0 = 2 * j;
    if (j + 1 < np)      waitcnt_vm<4>();   // pair j done; next pair in flight
    else if (odd)        waitcnt_vm<2>();   // tail tile still in flight
    else                 waitcnt_vm<0>();
    asm volatile("s_barrier" ::: "memory");

    tile_body(t0,     t0 & 3);
    tile_body(t0 + 1, (t0 + 1) & 3);

    lds_drain_barrier();   // reads done -> pair-j bufs safe for re-stage
    const int tp = t0 + 4;
    if (tp < ntiles)     stage(tp & 3, tp * 64);
    if (tp + 1 < ntiles) stage((tp + 1) & 3, (tp + 1) * 64);
  }
  if (odd) {
    const int t = ntiles - 1;
    waitcnt_vm<0>();
    asm volatile("s_barrier" ::: "memory");
    tile_body(t, t & 3);
    lds_drain_barrier();   // all K/V reads done before epilogue reuses LDS
  }

  // ---- cross-k-half combine (reuse dead K/V/P LDS as fp32 scratch) ----
  float sH = lsumH; sH += __shfl_xor(sH, 16); sH += __shfl_xor(sH, 32);
  float sL = lsumL; sL += __shfl_xor(sL, 16); sL += __shfl_xor(sL, 32);
  float* oshH = (float*)Ks;              // [4][64][16] = 16 KiB <= 32 KiB
  float* oshL = (float*)Vs;              // [4][64][16]
  float* lsh  = (float*)&Pq[0][0][0];    // [2][4][16] = 512 B

  if (kw == 1) {
    const int base = (wq * 64 + lane) * 16;
#pragma unroll
    for (int ds = 0; ds < 4; ++ds) {
      *(floatx4*)(oshH + base + ds * 4) = otH[ds];
      *(floatx4*)(oshL + base + ds * 4) = otL[ds];
    }
    if (lane < 16) {
      lsh[wq * 16 + lane]      = sH;
      lsh[64 + wq * 16 + lane] = sL;
    }
  }
  __syncthreads();
  if (kw == 0) {
    const int base = (wq * 64 + lane) * 16;
#pragma unroll
    for (int ds = 0; ds < 4; ++ds) {
      otH[ds] += *(const floatx4*)(oshH + base + ds * 4);
      otL[ds] += *(const floatx4*)(oshL + base + ds * 4);
    }
    sH += lsh[wq * 16 + lo];
    sL += lsh[64 + wq * 16 + lo];

    auto finish = [&](floatx4* ot, float stot, int qw) {
      const float inv = 1.0f / stot;
#pragma unroll
      for (int ds = 0; ds < 4; ++ds) {
        uint2 o;
        o.x = pk_bf16(ot[ds][0] * inv, ot[ds][1] * inv);
        o.y = pk_bf16(ot[ds][2] * inv, ot[ds][3] * inv);
        *(uint2*)(y + (size_t)(b * LL + qw + lo) * (HH * HDD) + h * HDD + ds * 16 + g * 4) = o;
      }
    };
    finish(otH, sH, qHw);
    finish(otL, sL, qLw);
  }
}

// ---------------------------------------------------------------------------
// Launch (R3 geometry: all grids >= 2 blocks/CU or exactly CU-balanced)
// ---------------------------------------------------------------------------
extern "C" void kernel_launch(void* const* d_in, const int* in_sizes, int n_in,
                              void* d_out, int out_size, void* d_ws, size_t ws_size,
                              hipStream_t stream) {
  const float* x   = (const float*)d_in[0];  // [4096][1024]
  const float* Wq  = (const float*)d_in[1];  // [1024][1024]
  const float* Wkv = (const float*)d_in[2];  // [1024][256]
  const float* Wku = (const float*)d_in[3];  // [256][1024]
  const float* Wvu = (const float*)d_in[4];  // [256][1024]
  const float* Wo  = (const float*)d_in[5];  // [1024][1024]
  float* out = (float*)d_out;                // [4096][1024] fp32

  // workspace (bf16 elements)
  unsigned short* xb     = (unsigned short*)d_ws;          // 4096x1024
  unsigned short* WqT    = xb + (size_t)MTOT * DD;         // 1024x1024 [N][K]
  unsigned short* WkvT   = WqT + 1024 * 1024;              // 256x1024
  unsigned short* WkuT   = WkvT + 256 * 1024;              // 1024x256
  unsigned short* WvuT   = WkuT + 1024 * 256;              // 1024x256
  unsigned short* WoT    = WvuT + 1024 * 256;              // 1024x1024
  unsigned short* latent = WoT + 1024 * 1024;              // 4096x256
  unsigned short* Qh     = latent + (size_t)MTOT * LDIM;   // 4096x1024
  unsigned short* Kh     = Qh + (size_t)MTOT * DD;
  unsigned short* Vt     = Kh + (size_t)MTOT * DD;
  unsigned short* y      = Vt + (size_t)MTOT * DD;

  // prep
  cast_bf16<<<dim3(MTOT * DD / 1024), dim3(256), 0, stream>>>(x, xb, MTOT * DD / 4);
  transpose_cast5<<<dim3(32, 32, 5), dim3(32, 8), 0, stream>>>(
      Wq, Wkv, Wku, Wvu, Wo, WqT, WkvT, WkuT, WvuT, WoT);

  // fused Q + latent:  [4096,1024] x [1024, 1024+256]   (128x64, BK=64)
  gemm2<1, 128, 64, 64><<<dim3(MTOT / 128, 1280 / 64), dim3(256), 0, stream>>>(
      xb, WqT, WkvT, Qh, latent, MTOT, 1280, DD, 1024);
  // fused K + V:       [4096,256] x [256, 1024+1024]    (128x128, BK=64)
  gemm2<2, 128, 128, 64><<<dim3(MTOT / 128, 2048 / 128), dim3(256), 0, stream>>>(
      latent, WkuT, WvuT, Kh, Vt, MTOT, 2048, LDIM, 1024);

  // attention (paired-tile k-split flash v13 + setprio; h fastest for XCD L2)
  flash_mfma13<<<dim3(HH, BB, 16), dim3(512), 0, stream>>>(Qh, Kh, Vt, y);

  // output projection (fp32 out; 128x64, BK=64)
  gemm2<0, 128, 64, 64><<<dim3(MTOT / 128, DD / 64), dim3(256), 0, stream>>>(
      y, WoT, nullptr, out, nullptr, MTOT, DD, DD, DD);
}